// Round 1
// baseline (20777.641 us; speedup 1.0000x reference)
//
#include <hip/hip_runtime.h>
#include <stdint.h>

// LSTM: B=256, T=1024, I=64, H=256, O=1. fp32 in/out, bf16 MFMA internally.
//
// Decomposition: 256 blocks = 32 batch-groups (8 batches each) x 8 gate-slices
// (128 gate rows each = 32 hidden units x 4 gates). Weights register-resident
// as bf16 MFMA B-fragments (80 KB/block). Per step each block computes its
// 8x128 gate pre-activations with mfma_f32_16x16x32_bf16 (K=320 = 64 x-part +
// 256 h-part), applies nonlinearities, exchanges gate tiles via LDS, updates
// c/h for its 8x32 (batch x hidden) slice, publishes h (bf16) to a
// double-buffered global buffer and bumps a per-(group,slice) flag
// (agent-scope release). Peers spin on the 8 flags before reading h.
// Flags need no init: d_ws poison 0xAAAAAAAA < 1 as signed int.

#define B_ 256
#define T_ 1024
#define I_ 64
#define H_ 256
#define NSLICE 8
#define NGROUP 32
#define MB 8      /* batches per group  */
#define HB 32     /* hidden units per block */

typedef float floatx4 __attribute__((ext_vector_type(4)));
typedef __bf16 bf16x8 __attribute__((ext_vector_type(8)));
typedef unsigned short ushortx8 __attribute__((ext_vector_type(8)));

#define HBUF_ELEMS (NGROUP * MB * H_)          /* one parity buffer, ushorts */
#define FLAG_STRIDE 16                          /* ints; pad flags to 64B    */

__device__ __forceinline__ unsigned short f2bf(float f) {
  unsigned u = __builtin_bit_cast(unsigned, f);
  u = (u + 0x7FFFu + ((u >> 16) & 1u)) >> 16;   // RNE
  return (unsigned short)u;
}
__device__ __forceinline__ float bf2f(unsigned short h) {
  unsigned u = ((unsigned)h) << 16;
  return __builtin_bit_cast(float, u);
}
__device__ __forceinline__ ushortx8 pack8(floatx4 a, floatx4 b) {
  ushortx8 u;
  u[0] = f2bf(a[0]); u[1] = f2bf(a[1]); u[2] = f2bf(a[2]); u[3] = f2bf(a[3]);
  u[4] = f2bf(b[0]); u[5] = f2bf(b[1]); u[6] = f2bf(b[2]); u[7] = f2bf(b[3]);
  return u;
}
__device__ __forceinline__ float fast_sig(float v) {
  return 1.0f / (1.0f + __expf(-v));
}
__device__ __forceinline__ float fast_tanh(float v) {
  float e = __expf(2.0f * v);
  return 1.0f - 2.0f / (e + 1.0f);
}

__global__ __launch_bounds__(256, 1) void lstm_main(
    const float* __restrict__ x, const float* __restrict__ W_ih,
    const float* __restrict__ W_hh, const float* __restrict__ b_ih,
    const float* __restrict__ b_hh, unsigned short* __restrict__ hbuf,
    int* __restrict__ flags) {
  const int tid = threadIdx.x;
  const int bid = blockIdx.x;
  const int s = bid >> 5;     // slice 0..7  (bid%8 == g%8 -> group same-XCD)
  const int g = bid & 31;     // group 0..31
  const int w = tid >> 6;     // wave id == gate type (i,f,g,o)
  const int lane = tid & 63;
  const int ln = lane & 15;   // MFMA n (gate-row within tile) / A m (batch)
  const int lk = lane >> 4;   // MFMA k-subgroup (8 elems each)

  __shared__ float xch[4][2][16][8];  // [gate][jtile][n][m]

  // ---- preload weight B-fragments (bf16) + bias, once ----
  // rows of [W_ih | W_hh]: row = w*256 + s*32 + j*16 + ln; BT layout [N][K].
  ushortx8 wf[2][10];
  float bias[2];
#pragma unroll
  for (int j = 0; j < 2; ++j) {
    const int row = w * 256 + s * HB + j * 16 + ln;
    bias[j] = b_ih[row] + b_hh[row];
#pragma unroll
    for (int kc = 0; kc < 10; ++kc) {
      const int kk = kc * 32 + lk * 8;
      const float* src = (kk < I_) ? (W_ih + (size_t)row * I_ + kk)
                                   : (W_hh + (size_t)row * H_ + (kk - I_));
      floatx4 f0 = *(const floatx4*)src;
      floatx4 f1 = *(const floatx4*)(src + 4);
      wf[j][kc] = pack8(f0, f1);
    }
  }

  // A-side roles
  const int mb = ln & 7;                       // batch row (m>=8 duplicates)
  const float* xrow = x + ((size_t)(g * MB + mb)) * T_ * I_;
  // update-phase roles: thread = (m, hidden_local)
  const int um = tid >> 5;                     // 0..7 batch
  const int uh = tid & 31;                     // 0..31 hidden local
  const int uj = uh >> 4, un = uh & 15;
  float c_reg = 0.0f;

  int* const myflag = flags + (g * NSLICE + s) * FLAG_STRIDE;

#pragma unroll 1
  for (int t = 0; t < T_; ++t) {
    ushortx8 af[10];
    // x-part A-fragments (fp32 -> bf16 on the fly)
#pragma unroll
    for (int kc = 0; kc < 2; ++kc) {
      const float* src = xrow + t * I_ + kc * 32 + lk * 8;
      floatx4 f0 = *(const floatx4*)src;
      floatx4 f1 = *(const floatx4*)(src + 4);
      af[kc] = pack8(f0, f1);
    }
    if (t > 0) {
      // wait for all 8 peer h-chunks of this group
      if (tid < NSLICE) {
        const int* fp = flags + (g * NSLICE + tid) * FLAG_STRIDE;
        while (__hip_atomic_load(fp, __ATOMIC_RELAXED,
                                 __HIP_MEMORY_SCOPE_AGENT) < t) {
        }
      }
      __syncthreads();
      __threadfence();  // agent acquire: invalidate L1/L2 so h reads are fresh
      const unsigned short* hsrc =
          hbuf + (size_t)(t & 1) * HBUF_ELEMS + (size_t)(g * MB + mb) * H_;
#pragma unroll
      for (int kc = 2; kc < 10; ++kc) {
        af[kc] = *(const ushortx8*)(hsrc + (kc - 2) * 32 + lk * 8);
      }
    } else {
#pragma unroll
      for (int kc = 2; kc < 10; ++kc) {
        ushortx8 z = {0, 0, 0, 0, 0, 0, 0, 0};
        af[kc] = z;
      }
    }

    // ---- MFMA: D[m][n] = sum_k A[m][k] * W[n][k], bias pre-loaded in acc ----
    floatx4 acc[2];
    acc[0] = (floatx4){bias[0], bias[0], bias[0], bias[0]};
    acc[1] = (floatx4){bias[1], bias[1], bias[1], bias[1]};
#pragma unroll
    for (int kc = 0; kc < 10; ++kc) {
      acc[0] = __builtin_amdgcn_mfma_f32_16x16x32_bf16(
          __builtin_bit_cast(bf16x8, af[kc]),
          __builtin_bit_cast(bf16x8, wf[0][kc]), acc[0], 0, 0, 0);
      acc[1] = __builtin_amdgcn_mfma_f32_16x16x32_bf16(
          __builtin_bit_cast(bf16x8, af[kc]),
          __builtin_bit_cast(bf16x8, wf[1][kc]), acc[1], 0, 0, 0);
    }

    // ---- nonlinearity (wave-uniform branch) + LDS exchange ----
#pragma unroll
    for (int j = 0; j < 2; ++j) {
      floatx4 v = acc[j];
      if (w == 2) {
        v[0] = fast_tanh(v[0]); v[1] = fast_tanh(v[1]);
        v[2] = fast_tanh(v[2]); v[3] = fast_tanh(v[3]);
      } else {
        v[0] = fast_sig(v[0]); v[1] = fast_sig(v[1]);
        v[2] = fast_sig(v[2]); v[3] = fast_sig(v[3]);
      }
      if (lk < 2) {  // valid m rows 0..7 live in lanes 0..31, m = lk*4+reg
        *(floatx4*)&xch[w][j][ln][lk * 4] = v;
      }
    }
    __syncthreads();

    // ---- c/h update: thread = (um, uh) ----
    float ig = xch[0][uj][un][um];
    float fg = xch[1][uj][un][um];
    float gg = xch[2][uj][un][um];
    float og = xch[3][uj][un][um];
    c_reg = fg * c_reg + ig * gg;
    float hv = og * fast_tanh(c_reg);
    hbuf[(size_t)((t + 1) & 1) * HBUF_ELEMS + (size_t)(g * MB + um) * H_ +
         s * HB + uh] = f2bf(hv);
    __syncthreads();  // drains vmcnt(0): all h stores of the block complete
    if (tid == 0) {
      __hip_atomic_store(myflag, t + 1, __ATOMIC_RELEASE,
                         __HIP_MEMORY_SCOPE_AGENT);
    }
  }
}

// out[b] = dot(h_T[b], fc_w) + fc_b. Final h lives in parity buffer 0
// (written at end of step 1023: (1023+1)&1 == 0), batch-major [256][256].
__global__ void lstm_fc(const unsigned short* __restrict__ hbuf,
                        const float* __restrict__ fc_w,
                        const float* __restrict__ fc_b,
                        float* __restrict__ out) {
  const int b = threadIdx.x;
  const unsigned short* h = hbuf + (size_t)b * H_;
  float sum = fc_b[0];
#pragma unroll 4
  for (int k = 0; k < H_; ++k) sum += bf2f(h[k]) * fc_w[k];
  out[b] = sum;
}

extern "C" void kernel_launch(void* const* d_in, const int* in_sizes, int n_in,
                              void* d_out, int out_size, void* d_ws,
                              size_t ws_size, hipStream_t stream) {
  const float* x    = (const float*)d_in[0];
  const float* W_ih = (const float*)d_in[1];
  const float* W_hh = (const float*)d_in[2];
  const float* b_ih = (const float*)d_in[3];
  const float* b_hh = (const float*)d_in[4];
  const float* fc_w = (const float*)d_in[5];
  const float* fc_b = (const float*)d_in[6];
  float* out = (float*)d_out;

  unsigned short* hbuf = (unsigned short*)d_ws;  // 2 parity buffers, 256 KB
  int* flags = (int*)((char*)d_ws + (size_t)2 * HBUF_ELEMS * sizeof(unsigned short));
  // flags: 32*8 ints padded to 64B each (16 KB); poison 0xAAAAAAAA < 1 signed,
  // so no init kernel is needed.

  lstm_main<<<dim3(NGROUP * NSLICE), dim3(256), 0, stream>>>(
      x, W_ih, W_hh, b_ih, b_hh, hbuf, flags);
  lstm_fc<<<dim3(1), dim3(256), 0, stream>>>(hbuf, fc_w, fc_b, out);
}

// Round 2
// 2460.716 us; speedup vs baseline: 8.4437x; 8.4437x over previous
//
#include <hip/hip_runtime.h>
#include <stdint.h>

// LSTM: B=256, T=1024, I=64, H=256, O=1. fp32 in/out, bf16 MFMA internally.
//
// 256 blocks = 32 batch-groups (8 batches) x 8 gate-slices (128 gate rows).
// Weights register-resident as bf16 MFMA B-fragments (80 KB/block).
// Cross-block h exchange: fine-grained cache-bypassing atomics (RELAXED,
// AGENT scope -> sc0/sc1, served at L3). NO __threadfence / RELEASE anywhere:
// those lower to whole-L2 buffer_inv/buffer_wbl2 per step, which was the
// 20 ms bottleneck in round 1. Ordering argument:
//   producer: write-through h stores -> __syncthreads() (each wave drains
//     vmcnt(0) before s_barrier) -> all h acked at L3 -> relaxed flag store.
//   consumer: relaxed flag poll sees t -> h loads issued after -> L3 already
//     has h. Correct for any L3 slicing since h was acked before flag issued.

#define B_ 256
#define T_ 1024
#define I_ 64
#define H_ 256
#define NSLICE 8
#define NGROUP 32
#define MB 8      /* batches per group  */
#define HB 32     /* hidden units per block */

typedef float floatx4 __attribute__((ext_vector_type(4)));
typedef __bf16 bf16x8 __attribute__((ext_vector_type(8)));
typedef unsigned short ushortx8 __attribute__((ext_vector_type(8)));

#define HBUF_ELEMS (NGROUP * MB * H_)          /* one parity buffer, ushorts */
#define FLAG_STRIDE 16                          /* ints; pad flags to 64B    */
#define HROW 272                                /* padded h_lds row (ushorts) */

__device__ __forceinline__ unsigned short f2bf(float f) {
  unsigned u = __builtin_bit_cast(unsigned, f);
  u = (u + 0x7FFFu + ((u >> 16) & 1u)) >> 16;   // RNE
  return (unsigned short)u;
}
__device__ __forceinline__ float bf2f(unsigned u16) {
  unsigned u = u16 << 16;
  return __builtin_bit_cast(float, u);
}
__device__ __forceinline__ ushortx8 pack8(floatx4 a, floatx4 b) {
  ushortx8 u;
  u[0] = f2bf(a[0]); u[1] = f2bf(a[1]); u[2] = f2bf(a[2]); u[3] = f2bf(a[3]);
  u[4] = f2bf(b[0]); u[5] = f2bf(b[1]); u[6] = f2bf(b[2]); u[7] = f2bf(b[3]);
  return u;
}
__device__ __forceinline__ float fast_sig(float v) {
  return 1.0f / (1.0f + __expf(-v));
}
__device__ __forceinline__ float fast_tanh(float v) {
  float e = __expf(2.0f * v);
  return 1.0f - 2.0f / (e + 1.0f);
}

__global__ __launch_bounds__(256, 1) void lstm_main(
    const float* __restrict__ x, const float* __restrict__ W_ih,
    const float* __restrict__ W_hh, const float* __restrict__ b_ih,
    const float* __restrict__ b_hh, unsigned short* __restrict__ hbuf,
    int* __restrict__ flags) {
  const int tid = threadIdx.x;
  const int bid = blockIdx.x;
  const int s = bid >> 5;     // slice 0..7  (bid%8 == g%8 -> group same-XCD)
  const int g = bid & 31;     // group 0..31
  const int w = tid >> 6;     // wave id == gate type (i,f,g,o)
  const int lane = tid & 63;
  const int ln = lane & 15;   // MFMA n (gate-row within tile) / A m (batch)
  const int lk = lane >> 4;   // MFMA k-subgroup (8 elems each)

  __shared__ float xch[4][2][16][8];                    // [gate][j][n][m]
  __shared__ __align__(16) unsigned short h_lds[MB][HROW];
  __shared__ unsigned short hpack[MB][HB];

  // ---- preload weight B-fragments (bf16) + bias, once ----
  ushortx8 wf[2][10];
  float bias[2];
#pragma unroll
  for (int j = 0; j < 2; ++j) {
    const int row = w * 256 + s * HB + j * 16 + ln;
    bias[j] = b_ih[row] + b_hh[row];
#pragma unroll
    for (int kc = 0; kc < 10; ++kc) {
      const int kk = kc * 32 + lk * 8;
      const float* src = (kk < I_) ? (W_ih + (size_t)row * I_ + kk)
                                   : (W_hh + (size_t)row * H_ + (kk - I_));
      floatx4 f0 = *(const floatx4*)src;
      floatx4 f1 = *(const floatx4*)(src + 4);
      wf[j][kc] = pack8(f0, f1);
    }
  }

  const int mb = ln & 7;                       // batch row (m>=8 duplicates)
  const float* xrow = x + ((size_t)(g * MB + mb)) * T_ * I_;
  // cooperative h-load roles: thread -> 4 dwords of the 1024-dword image
  const int hb_batch = tid >> 5;
  const int hb_off = (tid & 31) * 4;           // dword offset within row
  // update-phase roles
  const int um = tid >> 5;                     // 0..7 batch
  const int uh = tid & 31;                     // 0..31 hidden local
  const int uj = uh >> 4, un = uh & 15;
  float c_reg = 0.0f;

  int* const myflag = flags + (g * NSLICE + s) * FLAG_STRIDE;

#pragma unroll 1
  for (int t = 0; t < T_; ++t) {
    ushortx8 af[10];
    // x-part A-fragments (fp32 -> bf16 on the fly); issue before the poll
#pragma unroll
    for (int kc = 0; kc < 2; ++kc) {
      const float* src = xrow + t * I_ + kc * 32 + lk * 8;
      floatx4 f0 = *(const floatx4*)src;
      floatx4 f1 = *(const floatx4*)(src + 4);
      af[kc] = pack8(f0, f1);
    }
    if (t > 0) {
      // wait for all 8 peer h-chunks of this group (relaxed, cache-bypass)
      if (tid < NSLICE) {
        const int* fp = flags + (g * NSLICE + tid) * FLAG_STRIDE;
        while (__hip_atomic_load(fp, __ATOMIC_RELAXED,
                                 __HIP_MEMORY_SCOPE_AGENT) < t) {
        }
      }
      __syncthreads();
      // cooperative bypass-load of this group's full h (4 KB) into LDS
      {
        const unsigned int* hsrc32 =
            (const unsigned int*)(hbuf + (size_t)(t & 1) * HBUF_ELEMS +
                                  (size_t)(g * MB + hb_batch) * H_) +
            hb_off;
        unsigned int d0 = __hip_atomic_load(hsrc32 + 0, __ATOMIC_RELAXED,
                                            __HIP_MEMORY_SCOPE_AGENT);
        unsigned int d1 = __hip_atomic_load(hsrc32 + 1, __ATOMIC_RELAXED,
                                            __HIP_MEMORY_SCOPE_AGENT);
        unsigned int d2 = __hip_atomic_load(hsrc32 + 2, __ATOMIC_RELAXED,
                                            __HIP_MEMORY_SCOPE_AGENT);
        unsigned int d3 = __hip_atomic_load(hsrc32 + 3, __ATOMIC_RELAXED,
                                            __HIP_MEMORY_SCOPE_AGENT);
        unsigned int* dst = (unsigned int*)&h_lds[hb_batch][hb_off * 2];
        dst[0] = d0; dst[1] = d1; dst[2] = d2; dst[3] = d3;
      }
      __syncthreads();
      const unsigned short* hrow = &h_lds[mb][0];
#pragma unroll
      for (int kc = 2; kc < 10; ++kc) {
        af[kc] = *(const ushortx8*)(hrow + (kc - 2) * 32 + lk * 8);
      }
    } else {
#pragma unroll
      for (int kc = 2; kc < 10; ++kc) {
        ushortx8 z = {0, 0, 0, 0, 0, 0, 0, 0};
        af[kc] = z;
      }
    }

    // ---- MFMA: D[m][n] = sum_k A[m][k] * W[n][k], bias in acc ----
    floatx4 acc[2];
    acc[0] = (floatx4){bias[0], bias[0], bias[0], bias[0]};
    acc[1] = (floatx4){bias[1], bias[1], bias[1], bias[1]};
#pragma unroll
    for (int kc = 0; kc < 10; ++kc) {
      acc[0] = __builtin_amdgcn_mfma_f32_16x16x32_bf16(
          __builtin_bit_cast(bf16x8, af[kc]),
          __builtin_bit_cast(bf16x8, wf[0][kc]), acc[0], 0, 0, 0);
      acc[1] = __builtin_amdgcn_mfma_f32_16x16x32_bf16(
          __builtin_bit_cast(bf16x8, af[kc]),
          __builtin_bit_cast(bf16x8, wf[1][kc]), acc[1], 0, 0, 0);
    }

    // ---- nonlinearity (wave-uniform branch) + LDS exchange ----
#pragma unroll
    for (int j = 0; j < 2; ++j) {
      floatx4 v = acc[j];
      if (w == 2) {
        v[0] = fast_tanh(v[0]); v[1] = fast_tanh(v[1]);
        v[2] = fast_tanh(v[2]); v[3] = fast_tanh(v[3]);
      } else {
        v[0] = fast_sig(v[0]); v[1] = fast_sig(v[1]);
        v[2] = fast_sig(v[2]); v[3] = fast_sig(v[3]);
      }
      if (lk < 2) {  // valid m rows 0..7 live in lanes 0..31, m = lk*4+reg
        *(floatx4*)&xch[w][j][ln][lk * 4] = v;
      }
    }
    __syncthreads();

    // ---- c/h update: thread = (um, uh) ----
    float ig = xch[0][uj][un][um];
    float fg = xch[1][uj][un][um];
    float gg = xch[2][uj][un][um];
    float og = xch[3][uj][un][um];
    c_reg = fg * c_reg + ig * gg;
    float hv = og * fast_tanh(c_reg);
    hpack[um][uh] = f2bf(hv);
    __syncthreads();
    // pack pairs -> dword bypass stores (write-through to L3)
    if (tid < 128) {
      const int pm = tid >> 4;   // batch 0..7
      const int pp = tid & 15;   // dword index -> hidden 2*pp, 2*pp+1
      unsigned int v = (unsigned int)hpack[pm][2 * pp] |
                       ((unsigned int)hpack[pm][2 * pp + 1] << 16);
      unsigned int* dst =
          (unsigned int*)(hbuf + (size_t)((t + 1) & 1) * HBUF_ELEMS +
                          (size_t)(g * MB + pm) * H_ + s * HB) +
          pp;
      __hip_atomic_store(dst, v, __ATOMIC_RELAXED, __HIP_MEMORY_SCOPE_AGENT);
    }
    __syncthreads();  // each wave drains vmcnt(0) before barrier -> h visible
    if (tid == 0) {
      __hip_atomic_store(myflag, t + 1, __ATOMIC_RELAXED,
                         __HIP_MEMORY_SCOPE_AGENT);
    }
  }
}

// out[b] = dot(h_T[b], fc_w) + fc_b. Final h in parity buffer 0 (step 1023
// writes (1023+1)&1 == 0). Bypass loads: avoids stale-L2 lines from the
// previous graph replay.
__global__ void lstm_fc(const unsigned short* __restrict__ hbuf,
                        const float* __restrict__ fc_w,
                        const float* __restrict__ fc_b,
                        float* __restrict__ out) {
  const int b = threadIdx.x;
  const unsigned int* h32 = (const unsigned int*)(hbuf + (size_t)b * H_);
  float sum = fc_b[0];
#pragma unroll 8
  for (int k = 0; k < H_ / 2; ++k) {
    unsigned int v =
        __hip_atomic_load(h32 + k, __ATOMIC_RELAXED, __HIP_MEMORY_SCOPE_AGENT);
    sum += bf2f(v & 0xffffu) * fc_w[2 * k] + bf2f(v >> 16) * fc_w[2 * k + 1];
  }
  out[b] = sum;
}

extern "C" void kernel_launch(void* const* d_in, const int* in_sizes, int n_in,
                              void* d_out, int out_size, void* d_ws,
                              size_t ws_size, hipStream_t stream) {
  const float* x    = (const float*)d_in[0];
  const float* W_ih = (const float*)d_in[1];
  const float* W_hh = (const float*)d_in[2];
  const float* b_ih = (const float*)d_in[3];
  const float* b_hh = (const float*)d_in[4];
  const float* fc_w = (const float*)d_in[5];
  const float* fc_b = (const float*)d_in[6];
  float* out = (float*)d_out;

  unsigned short* hbuf = (unsigned short*)d_ws;  // 2 parity buffers, 256 KB
  int* flags = (int*)((char*)d_ws + (size_t)2 * HBUF_ELEMS * sizeof(unsigned short));
  // flags poison 0xAAAAAAAA < 1 signed => no init kernel needed.

  lstm_main<<<dim3(NGROUP * NSLICE), dim3(256), 0, stream>>>(
      x, W_ih, W_hh, b_ih, b_hh, hbuf, flags);
  lstm_fc<<<dim3(1), dim3(256), 0, stream>>>(hbuf, fc_w, fc_b, out);
}

// Round 3
// 2355.742 us; speedup vs baseline: 8.8200x; 1.0446x over previous
//
#include <hip/hip_runtime.h>
#include <stdint.h>

// LSTM: B=256, T=1024, I=64, H=256, O=1. fp32 in/out, bf16 MFMA internally.
//
// 256 blocks = 32 batch-groups (8 batches) x 8 gate-slices (128 gate rows).
// Weights register-resident as bf16 MFMA B-fragments (80 KB/block).
//
// Cross-block h exchange, ONE L3 round trip (round-3 design): h is published
// as 8-byte single-copy-atomic units {payload dword = 2 bf16 h, tag dword =
// step number}, stored with relaxed cache-bypassing (AGENT-scope) stores.
// Consumers poll the units directly until tag==t; the payload arrives in the
// same atomic 8B, so NO producer-side vmcnt drain, NO separate flag, and NO
// separate bulk-load phase are needed. Double-buffered by step parity;
// safety: tag-t units are only overwritten at end of step t+1, which requires
// all peers to have completed poll(t) first (production of t+1 needs all
// slices' tag-t consumed) -> no unit is overwritten while still polled.
// Tag poison 0xAAAAAAAA never equals a live tag (1..1024) -> no init needed.

#define T_ 1024
#define I_ 64
#define H_ 256
#define NSLICE 8
#define NGROUP 32
#define MB 8      /* batches per group  */
#define HB 32     /* hidden units per block */
#define HROW 272  /* padded h_lds row (ushorts), 544 B = 34 x 16 B */

#define UNITS_PER_GROUP 1024                       /* 8B units per step */
#define UNITS_PER_PARITY (NGROUP * UNITS_PER_GROUP)

typedef float floatx4 __attribute__((ext_vector_type(4)));
typedef __bf16 bf16x8 __attribute__((ext_vector_type(8)));
typedef unsigned short ushortx8 __attribute__((ext_vector_type(8)));
typedef unsigned int uintx4 __attribute__((ext_vector_type(4)));
typedef unsigned int uint32;
typedef unsigned long long u64;

__device__ __forceinline__ float bf2f(uint32 u16) {
  uint32 u = u16 << 16;
  return __builtin_bit_cast(float, u);
}
__device__ __forceinline__ bf16x8 packbf8(floatx4 a, floatx4 b) {
  bf16x8 r;
  r[0] = (__bf16)a[0]; r[1] = (__bf16)a[1];
  r[2] = (__bf16)a[2]; r[3] = (__bf16)a[3];
  r[4] = (__bf16)b[0]; r[5] = (__bf16)b[1];
  r[6] = (__bf16)b[2]; r[7] = (__bf16)b[3];
  return r;
}
__device__ __forceinline__ float fast_sig(float v) {
  return 1.0f / (1.0f + __expf(-v));
}
__device__ __forceinline__ float fast_tanh(float v) {
  float e = __expf(2.0f * v);
  return 1.0f - 2.0f / (e + 1.0f);
}

__global__ __launch_bounds__(256, 1) void lstm_main(
    const float* __restrict__ x, const float* __restrict__ W_ih,
    const float* __restrict__ W_hh, const float* __restrict__ b_ih,
    const float* __restrict__ b_hh, u64* __restrict__ units) {
  const int tid = threadIdx.x;
  const int bid = blockIdx.x;
  const int s = bid >> 5;     // slice 0..7  (bid%8 == g%8 -> group same-XCD)
  const int g = bid & 31;     // group 0..31
  const int w = tid >> 6;     // wave id == gate type (i,f,g,o)
  const int lane = tid & 63;
  const int ln = lane & 15;   // MFMA n / A m
  const int lk = lane >> 4;   // MFMA k-subgroup (8 elems each)

  __shared__ float xch[4][2][16][8];                     // [gate][j][n][m]
  __shared__ __align__(16) unsigned short h_lds[MB][HROW];

  // zero h_lds (h_0 = 0 for t=0; also clears pad)
  {
    uint32* p = (uint32*)&h_lds[0][0];
    for (int i = tid; i < MB * HROW / 2; i += 256) p[i] = 0u;
  }

  // ---- preload weight B-fragments (bf16) + bias, once ----
  bf16x8 wf[2][10];
  float bias[2];
#pragma unroll
  for (int j = 0; j < 2; ++j) {
    const int row = w * 256 + s * HB + j * 16 + ln;
    bias[j] = b_ih[row] + b_hh[row];
#pragma unroll
    for (int kc = 0; kc < 10; ++kc) {
      const int kk = kc * 32 + lk * 8;
      const float* src = (kk < I_) ? (W_ih + (size_t)row * I_ + kk)
                                   : (W_hh + (size_t)row * H_ + (kk - I_));
      floatx4 f0 = *(const floatx4*)src;
      floatx4 f1 = *(const floatx4*)(src + 4);
      wf[j][kc] = packbf8(f0, f1);
    }
  }

  const int mb = ln & 7;                       // batch row (m>=8 duplicates)
  const float* xrow = x + ((size_t)(g * MB + mb)) * T_ * I_;
  // update-phase roles
  const int um = tid >> 5;                     // 0..7 batch
  const int uh = tid & 31;                     // 0..31 hidden local
  const int uj = uh >> 4, un = uh & 15;
  float c_reg = 0.0f;

  const size_t gbase = (size_t)g * UNITS_PER_GROUP;

  __syncthreads();

#pragma unroll 1
  for (int t = 0; t < T_; ++t) {
    // x loads issued first so they overlap the poll
    floatx4 xf0, xf1, xf2, xf3;
    {
      const float* src = xrow + t * I_ + lk * 8;
      xf0 = *(const floatx4*)(src);
      xf1 = *(const floatx4*)(src + 4);
      xf2 = *(const floatx4*)(src + 32);
      xf3 = *(const floatx4*)(src + 36);
    }

    if (t > 0) {
      // poll 4 contiguous units per thread; tag==t means payload valid
      const u64* up =
          units + (size_t)(t & 1) * UNITS_PER_PARITY + gbase + tid * 4;
      u64 v0, v1, v2, v3;
      bool ok;
      do {
        v0 = __hip_atomic_load(up + 0, __ATOMIC_RELAXED,
                               __HIP_MEMORY_SCOPE_AGENT);
        v1 = __hip_atomic_load(up + 1, __ATOMIC_RELAXED,
                               __HIP_MEMORY_SCOPE_AGENT);
        v2 = __hip_atomic_load(up + 2, __ATOMIC_RELAXED,
                               __HIP_MEMORY_SCOPE_AGENT);
        v3 = __hip_atomic_load(up + 3, __ATOMIC_RELAXED,
                               __HIP_MEMORY_SCOPE_AGENT);
        ok = ((uint32)(v0 >> 32) == (uint32)t) &&
             ((uint32)(v1 >> 32) == (uint32)t) &&
             ((uint32)(v2 >> 32) == (uint32)t) &&
             ((uint32)(v3 >> 32) == (uint32)t);
      } while (!__all(ok));
      uintx4 d;
      d[0] = (uint32)v0; d[1] = (uint32)v1;
      d[2] = (uint32)v2; d[3] = (uint32)v3;
      // unit u = m*128 + dword; tid*4 = (tid>>5)*128 + (tid&31)*4
      uint32* dst = (uint32*)&h_lds[tid >> 5][0] + (tid & 31) * 4;
      *(uintx4*)dst = d;  // 16B aligned
    }
    __syncthreads();  // S1: h_lds ready

    bf16x8 af[10];
    af[0] = packbf8(xf0, xf1);
    af[1] = packbf8(xf2, xf3);
    const unsigned short* hrow = &h_lds[mb][0];
#pragma unroll
    for (int kc = 2; kc < 10; ++kc) {
      af[kc] =
          __builtin_bit_cast(bf16x8, *(const ushortx8*)(hrow + (kc - 2) * 32 +
                                                        lk * 8));
    }

    // ---- MFMA: D[m][n] = sum_k A[m][k] * W[n][k], bias in acc ----
    floatx4 acc[2];
    acc[0] = (floatx4){bias[0], bias[0], bias[0], bias[0]};
    acc[1] = (floatx4){bias[1], bias[1], bias[1], bias[1]};
#pragma unroll
    for (int kc = 0; kc < 10; ++kc) {
      acc[0] = __builtin_amdgcn_mfma_f32_16x16x32_bf16(af[kc], wf[0][kc],
                                                       acc[0], 0, 0, 0);
      acc[1] = __builtin_amdgcn_mfma_f32_16x16x32_bf16(af[kc], wf[1][kc],
                                                       acc[1], 0, 0, 0);
    }

    // ---- nonlinearity (wave-uniform branch) + LDS exchange ----
#pragma unroll
    for (int j = 0; j < 2; ++j) {
      floatx4 v = acc[j];
      if (w == 2) {
        v[0] = fast_tanh(v[0]); v[1] = fast_tanh(v[1]);
        v[2] = fast_tanh(v[2]); v[3] = fast_tanh(v[3]);
      } else {
        v[0] = fast_sig(v[0]); v[1] = fast_sig(v[1]);
        v[2] = fast_sig(v[2]); v[3] = fast_sig(v[3]);
      }
      if (lk < 2) {  // valid m rows 0..7 live in lanes 0..31, m = lk*4+reg
        *(floatx4*)&xch[w][j][ln][lk * 4] = v;
      }
    }
    __syncthreads();  // S2: gates ready

    // ---- c/h update: thread = (um, uh) ----
    float ig = xch[0][uj][un][um];
    float fg = xch[1][uj][un][um];
    float gg = xch[2][uj][un][um];
    float og = xch[3][uj][un][um];
    c_reg = fg * c_reg + ig * gg;
    float hv = og * fast_tanh(c_reg);

    // pair-pack via shfl, publish 8B unit {h pair, tag t+1}
    unsigned short hb = __builtin_bit_cast(unsigned short, (__bf16)hv);
    int pv = __shfl_xor((int)hb, 1);
    if ((uh & 1) == 0) {
      uint32 dword = (uint32)hb | ((uint32)(unsigned short)pv << 16);
      u64 val = (u64)dword | ((u64)(uint32)(t + 1) << 32);
      u64* dst = units + (size_t)((t + 1) & 1) * UNITS_PER_PARITY + gbase +
                 (um * 128 + s * 16 + (uh >> 1));
      __hip_atomic_store(dst, val, __ATOMIC_RELAXED,
                         __HIP_MEMORY_SCOPE_AGENT);
    }
  }
}

// out[b] = dot(h_T[b], fc_w) + fc_b. Final h = tag-1024 units in parity 0
// ((1023+1)&1 == 0). Bypass loads avoid stale cache lines across replays.
__global__ void lstm_fc(const u64* __restrict__ units,
                        const float* __restrict__ fc_w,
                        const float* __restrict__ fc_b,
                        float* __restrict__ out) {
  const int b = threadIdx.x;
  const int g = b >> 3, m = b & 7;
  const u64* base = units + (size_t)g * UNITS_PER_GROUP + m * 128;
  float sum = fc_b[0];
#pragma unroll 8
  for (int d = 0; d < 128; ++d) {
    u64 v = __hip_atomic_load(base + d, __ATOMIC_RELAXED,
                              __HIP_MEMORY_SCOPE_AGENT);
    uint32 lo = (uint32)v;
    sum += bf2f(lo & 0xffffu) * fc_w[2 * d] + bf2f(lo >> 16) * fc_w[2 * d + 1];
  }
  out[b] = sum;
}

extern "C" void kernel_launch(void* const* d_in, const int* in_sizes, int n_in,
                              void* d_out, int out_size, void* d_ws,
                              size_t ws_size, hipStream_t stream) {
  const float* x    = (const float*)d_in[0];
  const float* W_ih = (const float*)d_in[1];
  const float* W_hh = (const float*)d_in[2];
  const float* b_ih = (const float*)d_in[3];
  const float* b_hh = (const float*)d_in[4];
  const float* fc_w = (const float*)d_in[5];
  const float* fc_b = (const float*)d_in[6];
  float* out = (float*)d_out;

  u64* units = (u64*)d_ws;  // 2 parities x 32 groups x 1024 units x 8B = 512KB
  // tag poison 0xAAAAAAAA != any live tag (1..1024) => no init needed.

  lstm_main<<<dim3(NGROUP * NSLICE), dim3(256), 0, stream>>>(
      x, W_ih, W_hh, b_ih, b_hh, units);
  lstm_fc<<<dim3(1), dim3(256), 0, stream>>>(units, fc_w, fc_b, out);
}